// Round 4
// baseline (359.192 us; speedup 1.0000x reference)
//
#include <hip/hip_runtime.h>
#include <hip/hip_bf16.h>
#include <string.h>

#define NN   4096
#define NE   32768
#define NB   32
#define BKT  64   // per-src edge bucket capacity (deg ~ Poisson(8); P(>64) ~ 1e-30)
#define MSG_CHUNK 8

typedef __attribute__((ext_vector_type(8))) short short8;
typedef __attribute__((ext_vector_type(4))) float f4;

__device__ __forceinline__ float sigf(float x) { return 1.0f / (1.0f + __expf(-x)); }
__device__ __forceinline__ short f2bf(float f) {
    __hip_bfloat16 h = __float2bfloat16(f);
    short s;
    memcpy(&s, &h, sizeof(short));
    return s;
}

// ---------------- k_setup: init + W2->W2F fragment repack + pre-MLP ----------------
// blocks 0..31: zero counters, init batch ranges
// blocks 32..223: enn_W2[l][g][k][o] -> W2F fragment-packed bf16 (MFMA-ready)
//   per-g layout (4096 shorts): pos(o,k) = (o>>4)<<10 | (k>>5)<<9 | ((k>>3)&3)<<7 | (o&15)<<3 | (k&7)
//   so a B-fragment load is W2F_g + sub*1024 + half*512 + lane*8 (fully coalesced).
// blocks 224..1247: pre-MLP (4 nodes per block) + zero agg
__global__ __launch_bounds__(256) void k_setup(const float* __restrict__ x,
        const float* __restrict__ W0, const float* __restrict__ b0,
        const float* __restrict__ W1, const float* __restrict__ b1,
        const float* __restrict__ W2, const float* __restrict__ b2,
        const float* __restrict__ enn_W2, __hip_bfloat16* __restrict__ W2F,
        float* __restrict__ out, float* __restrict__ agg,
        int* cnt_src, int* cnt_dst, int* bstart, int* bend) {
    int bid = blockIdx.x, t = threadIdx.x;
    if (bid < 32) {
        int i = bid * 256 + t;
        if (i < NN) cnt_src[i] = 0;
        else cnt_dst[i - NN] = 0;
        if (i < NB) { bstart[i] = 0x7FFFFFFF; bend[i] = 0; }
    } else if (bid < 224) {
        __shared__ __hip_bfloat16 tile[4096];
        size_t base = (size_t)(bid - 32) * 4096;
        for (int i = t; i < 4096; i += 256) {
            int k = i >> 6, o = i & 63;
            int pos = ((o >> 4) << 10) | ((k >> 5) << 9) | (((k >> 3) & 3) << 7)
                    | ((o & 15) << 3) | (k & 7);
            tile[pos] = __float2bfloat16(enn_W2[base + i]);
        }
        __syncthreads();
        for (int i = t; i < 4096; i += 256) W2F[base + i] = tile[i];
    } else {
        __shared__ float xr[4][128], ha[4][64], hb[4][64];
        int w = t >> 6, j = t & 63;
        int n = (bid - 224) * 4 + w;
        xr[w][j] = x[(size_t)n * 128 + j];
        xr[w][64 + j] = x[(size_t)n * 128 + 64 + j];
        agg[(size_t)n * 64 + j] = 0.f;
        float s = b0[j];
        #pragma unroll 8
        for (int k = 0; k < 128; ++k) s = fmaf(xr[w][k], W0[k * 64 + j], s);
        ha[w][j] = fmaxf(s, 0.f);
        s = b1[j];
        #pragma unroll 8
        for (int k = 0; k < 64; ++k) s = fmaf(ha[w][k], W1[k * 64 + j], s);
        hb[w][j] = fmaxf(s, 0.f);
        s = b2[j];
        #pragma unroll 8
        for (int k = 0; k < 64; ++k) s = fmaf(hb[w][k], W2[k * 64 + j], s);
        out[(size_t)n * 64 + j] = fmaxf(s, 0.f);
    }
}

// ---------------- k_bucket: bucket CSR fill + cnt_dst + batch ranges ----------------
__global__ __launch_bounds__(256) void k_bucket(const int* __restrict__ eidx,
        const float* __restrict__ ea, const int* __restrict__ bm,
        int* cnt_src, int* cnt_dst, int* csr_dst, float* csr_ea,
        int* bstart, int* bend) {
    int e = blockIdx.x * 256 + threadIdx.x;
    if (e < NE) {
        int s = eidx[e];
        int d = eidx[NE + e];
        int slot = atomicAdd(&cnt_src[s], 1);
        if (slot < BKT) {
            csr_dst[s * BKT + slot] = d;
            csr_ea[s * BKT + slot] = ea[e];
        }
        atomicAdd(&cnt_dst[d], 1);
    }
    if (e < NN) {
        int b = bm[e];
        atomicMin(&bstart[b], e);
        atomicMax(&bend[b], e + 1);
    }
}

// ---------------- k_fused: full-g P-tile MFMA in LDS + 1x-atomic message scatter ----
// One block = 8 src nodes, ALL 64 g (so each edge gets exactly ONE atomicAdd).
// LDS 74 KB -> 2 blocks/CU (8 waves/CU), grid 512 = exactly 2/CU, no tail.
// Phase 1: wave w computes P[n, g in [16w,16w+16), o] for all 8 nodes via MFMA
//   (A rows 8..15 duplicate nodes 0..7; quads 2,3 skip stores). Node region = 8 KB:
//   addr(n,g,o) = n*8192 + (g>>3)*1024 + o*16 + pair-dword, dword XOR'd by writer
//   quad for conflict-free ds_write (2 lanes/bank).
// Phase 2: wave w scatters messages for srcs {2w, 2w+1}; the quad-XOR is undone by
//   a wave-uniform dword swap keyed on the node's writer quad (nloc>>2).
__global__ __launch_bounds__(256, 2) void k_fused(const float* __restrict__ out,
        const __hip_bfloat16* __restrict__ W2F_l, const float* __restrict__ b2l,
        const float* __restrict__ W1l, const float* __restrict__ b1l,
        const int* __restrict__ cnt_src, const int* __restrict__ csr_dst,
        const float* __restrict__ csr_ea, float* __restrict__ agg) {
    __shared__ __hip_bfloat16 Pt[8 * 4096];           // 64 KB swizzled P tile
    __shared__ float outs[8][68];                     // fp32 node tile (padded)
    __shared__ float wlds[4][MSG_CHUNK][64];          // 8 KB We1 buffers (wave-private)
    int t = threadIdx.x, wave = t >> 6, lane = t & 63;
    int laneM = lane & 15, quad = lane >> 4;
    int n0 = blockIdx.x * 8;
    for (int i = t; i < 512; i += 256) outs[i >> 6][i & 63] = out[(size_t)n0 * 64 + i];
    __syncthreads();
    // A fragments (rows = 8 nodes, rows 8..15 duplicated; K = 64)
    short8 a0, a1;
    {
        const float* ar = &outs[laneM & 7][quad * 8];
        #pragma unroll
        for (int j = 0; j < 8; ++j) a0[j] = f2bf(ar[j]);
        const float* ar2 = &outs[laneM & 7][32 + quad * 8];
        #pragma unroll
        for (int j = 0; j < 8; ++j) a1[j] = f2bf(ar2[j]);
    }
    // BT (fp32, same summation order as the proven kernel): btr[u] = BT[n0+2*wave+u][lane]
    float btr[2] = {0.f, 0.f};
    for (int k = 0; k < 64; ++k) {
        float bv = b2l[k * 64 + lane];
        #pragma unroll
        for (int u = 0; u < 2; ++u) btr[u] = fmaf(outs[wave * 2 + u][k], bv, btr[u]);
    }
    // Phase 1: wave w owns g in [16w, 16w+16), as 8 adjacent pairs
    #pragma unroll 2
    for (int gp = 0; gp < 8; ++gp) {
        int gA = wave * 16 + gp * 2;                   // even g
        const __hip_bfloat16* BgA = W2F_l + (size_t)gA * 4096;
        const __hip_bfloat16* BgB = BgA + 4096;
        int c = gA >> 3;                               // g octet (0..7)
        int p = (gA >> 1) & 3;                         // pair-dword index in octet
        char* wb = (char*)Pt + (quad << 15) + (c << 10) + (laneM << 4)
                 + (((p ^ quad) & 3) << 2);
        #pragma unroll
        for (int sub = 0; sub < 4; ++sub) {
            short8 bA0 = *(const short8*)(BgA + sub * 1024 + lane * 8);
            short8 bA1 = *(const short8*)(BgA + sub * 1024 + 512 + lane * 8);
            short8 bB0 = *(const short8*)(BgB + sub * 1024 + lane * 8);
            short8 bB1 = *(const short8*)(BgB + sub * 1024 + 512 + lane * 8);
            f4 accA = {0.f, 0.f, 0.f, 0.f}, accB = {0.f, 0.f, 0.f, 0.f};
            accA = __builtin_amdgcn_mfma_f32_16x16x32_bf16(a0, bA0, accA, 0, 0, 0);
            accA = __builtin_amdgcn_mfma_f32_16x16x32_bf16(a1, bA1, accA, 0, 0, 0);
            accB = __builtin_amdgcn_mfma_f32_16x16x32_bf16(a0, bB0, accB, 0, 0, 0);
            accB = __builtin_amdgcn_mfma_f32_16x16x32_bf16(a1, bB1, accB, 0, 0, 0);
            if (quad < 2) {                            // nodes = quad*4+r in 0..7
                char* wbs = wb + (sub << 8);           // o += 16 -> 256 B
                #pragma unroll
                for (int r = 0; r < 4; ++r) {
                    unsigned pk = (unsigned)(unsigned short)f2bf(accA[r])
                                | ((unsigned)(unsigned short)f2bf(accB[r]) << 16);
                    *(unsigned*)(wbs + (r << 13)) = pk;    // node stride 8192 B
                }
            }
        }
    }
    __syncthreads();
    // Phase 2: full-g message scatter, 2 srcs per wave, one atomic per edge
    float w1v = W1l[lane], b1v = b1l[lane];
    for (int u = 0; u < 2; ++u) {
        int nloc = wave * 2 + u;
        int n = n0 + nloc;
        int deg = cnt_src[n];
        if (deg > BKT) deg = BKT;
        if (deg <= 0) continue;
        int wq = nloc >> 2;                            // writer quad (0 or 1)
        float preg[64];                                // P[n, g 0..63, o=lane]
        const char* Pn = (const char*)Pt + (nloc << 13);
        #pragma unroll
        for (int c = 0; c < 8; ++c) {
            uint4 vv = *(const uint4*)(Pn + (c << 10) + (lane << 4));
            unsigned d0 = vv.x, d1 = vv.y, d2 = vv.z, d3 = vv.w;
            if (wq & 1) { unsigned tt = d0; d0 = d1; d1 = tt; tt = d2; d2 = d3; d3 = tt; }
            union { unsigned u2; float f; } cv;
            cv.u2 = d0 << 16;          preg[c * 8 + 0] = cv.f;
            cv.u2 = d0 & 0xFFFF0000u;  preg[c * 8 + 1] = cv.f;
            cv.u2 = d1 << 16;          preg[c * 8 + 2] = cv.f;
            cv.u2 = d1 & 0xFFFF0000u;  preg[c * 8 + 3] = cv.f;
            cv.u2 = d2 << 16;          preg[c * 8 + 4] = cv.f;
            cv.u2 = d2 & 0xFFFF0000u;  preg[c * 8 + 5] = cv.f;
            cv.u2 = d3 << 16;          preg[c * 8 + 6] = cv.f;
            cv.u2 = d3 & 0xFFFF0000u;  preg[c * 8 + 7] = cv.f;
        }
        float bt = btr[u];
        const int* bdst = csr_dst + n * BKT;
        const float* bea = csr_ea + n * BKT;
        for (int c0 = 0; c0 < deg; c0 += MSG_CHUNK) {
            int cc = deg - c0;
            if (cc > MSG_CHUNK) cc = MSG_CHUNK;
            int dl = 0; float el = 0.f;
            if (lane < cc) { dl = bdst[c0 + lane]; el = bea[c0 + lane]; }
            for (int si = 0; si < cc; ++si) {
                float eav = __shfl(el, si, 64);
                wlds[wave][si][lane] = fmaxf(fmaf(eav, w1v, b1v), 0.f);   // We1 (lane = g)
            }
            for (int i = 0; i < cc; ++i) {
                int dst = __shfl(dl, i, 64);
                const float* wr = wlds[wave][i];
                float acc0 = bt, acc1 = 0.f, acc2 = 0.f, acc3 = 0.f;
                #pragma unroll
                for (int g = 0; g < 64; g += 16) {
                    float4 w0 = *(const float4*)(wr + g);
                    float4 w1 = *(const float4*)(wr + g + 4);
                    float4 w2 = *(const float4*)(wr + g + 8);
                    float4 w3 = *(const float4*)(wr + g + 12);
                    acc0 = fmaf(w0.x, preg[g], acc0);
                    acc0 = fmaf(w0.y, preg[g + 1], acc0);
                    acc0 = fmaf(w0.z, preg[g + 2], acc0);
                    acc0 = fmaf(w0.w, preg[g + 3], acc0);
                    acc1 = fmaf(w1.x, preg[g + 4], acc1);
                    acc1 = fmaf(w1.y, preg[g + 5], acc1);
                    acc1 = fmaf(w1.z, preg[g + 6], acc1);
                    acc1 = fmaf(w1.w, preg[g + 7], acc1);
                    acc2 = fmaf(w2.x, preg[g + 8], acc2);
                    acc2 = fmaf(w2.y, preg[g + 9], acc2);
                    acc2 = fmaf(w2.z, preg[g + 10], acc2);
                    acc2 = fmaf(w2.w, preg[g + 11], acc2);
                    acc3 = fmaf(w3.x, preg[g + 12], acc3);
                    acc3 = fmaf(w3.y, preg[g + 13], acc3);
                    acc3 = fmaf(w3.z, preg[g + 14], acc3);
                    acc3 = fmaf(w3.w, preg[g + 15], acc3);
                }
                float acc = (acc0 + acc1) + (acc2 + acc3);
                atomicAdd(&agg[(size_t)dst * 64 + lane], acc);   // un-normalized; /deg in GRU
            }
        }
    }
}

// ---------------- k_gru: conv (+deg-normalize) + GRU (+ agg re-zero) ----------------
__global__ __launch_bounds__(256) void k_gru(const float* __restrict__ out,
        float* __restrict__ agg, const int* __restrict__ cnt_dst,
        const float* __restrict__ rootW, const float* __restrict__ convb,
        const float* __restrict__ Wih, const float* __restrict__ Whh,
        const float* __restrict__ bih, const float* __restrict__ bhh,
        float* __restrict__ outn) {
    __shared__ float sh[4][64], sc[4][64];
    int t = threadIdx.x, w = t >> 6, j = t & 63;
    int n = blockIdx.x * 4 + w;
    float hj = out[(size_t)n * 64 + j];
    sh[w][j] = hj;
    int dg = cnt_dst[n];
    float invd = 1.0f / (float)(dg > 0 ? dg : 1);
    float av = agg[(size_t)n * 64 + j];
    agg[(size_t)n * 64 + j] = 0.f;          // pre-zero for next layer's atomics
    __syncthreads();
    float s = av * invd + convb[j];
    #pragma unroll 8
    for (int k = 0; k < 64; ++k) s = fmaf(sh[w][k], rootW[k * 64 + j], s);
    float conv = fmaxf(s, 0.f);
    sc[w][j] = conv;
    __syncthreads();
    float gir = bih[j], giz = bih[64 + j], gin = bih[128 + j];
    float ghr = bhh[j], ghz = bhh[64 + j], ghn = bhh[128 + j];
    #pragma unroll 4
    for (int k = 0; k < 64; ++k) {
        float c = sc[w][k], h = sh[w][k];
        gir = fmaf(c, Wih[k * 192 + j], gir);
        giz = fmaf(c, Wih[k * 192 + 64 + j], giz);
        gin = fmaf(c, Wih[k * 192 + 128 + j], gin);
        ghr = fmaf(h, Whh[k * 192 + j], ghr);
        ghz = fmaf(h, Whh[k * 192 + 64 + j], ghz);
        ghn = fmaf(h, Whh[k * 192 + 128 + j], ghn);
    }
    float r = sigf(gir + ghr);
    float z = sigf(giz + ghz);
    float nn = tanhf(gin + r * ghn);
    outn[(size_t)n * 64 + j] = (1.f - z) * nn + z * hj;
}

// ---------------- Set2Set (3 steps) + post-MLP: latency-minimal 256-thread version --
// One block = one batch (32 blocks). Thread t owns gate column t with its weight
// column in registers (no reduction barriers). cacheT[64][193] (pad 193) is
// conflict-free in BOTH read directions: e-phase thread=row (lane-consecutive at
// fixed d) and r-phase lane=d (banks (lane+row)%32). 7 barriers/step, 4 waves.
__global__ __launch_bounds__(256, 1) void k_s2s_post(const float* __restrict__ out,
        const int* __restrict__ bstart, const int* __restrict__ bend,
        const float* __restrict__ Wih, const float* __restrict__ Whh,
        const float* __restrict__ bih, const float* __restrict__ bhh,
        const float* __restrict__ pW0, const float* __restrict__ pb0,
        const float* __restrict__ pW1, const float* __restrict__ pb1,
        const float* __restrict__ pW2, const float* __restrict__ pb2,
        const float* __restrict__ pW3, const float* __restrict__ pb3,
        float* __restrict__ y) {
    __shared__ float cacheT[64 * 193];     // transposed node tile (49.4 KB)
    __shared__ float qs[128];              // [0:64]=q(hh), [64:128]=r_read
    __shared__ float hh_l[64];
    __shared__ float gates_l[256];
    __shared__ float ebuf[1024];
    __shared__ float redw[4], redw2[4];
    __shared__ float redbuf[4][64];
    __shared__ float tmp64[64];
    int t = threadIdx.x, wave = t >> 6, lane = t & 63;
    int b = blockIdx.x;
    int s0 = bstart[b], e0 = bend[b];
    int cnt = e0 - s0;
    if (cnt < 0) cnt = 0;
    if (cnt > 1024) cnt = 1024;
    int ccnt = cnt < 192 ? cnt : 192;
    // fill cacheT[d][row] from out rows (coalesced reads; writes bank (d+row)%32)
    for (int i = t; i < ccnt * 64; i += 256) {
        int row = i >> 6, d = i & 63;
        cacheT[d * 193 + row] = out[(size_t)(s0 + row) * 64 + d];
    }
    // per-thread gate-column weights (coalesced across lanes, loaded once)
    float wih[128], whh[64];
    #pragma unroll
    for (int j = 0; j < 128; ++j) wih[j] = Wih[(size_t)j * 256 + t];
    #pragma unroll
    for (int j = 0; j < 64; ++j) whh[j] = Whh[(size_t)j * 256 + t];
    float bsum = bih[t] + bhh[t];
    float ccr = 0.f;                       // cc for dim t (threads t<64 only)
    if (t < 128) qs[t] = 0.f;
    if (t < 64) hh_l[t] = 0.f;
    __syncthreads();
    const float4* qs4 = (const float4*)qs;
    const float4* hh4 = (const float4*)hh_l;
    for (int step = 0; step < 3; ++step) {
        // gates[t] = bias + qs . Wih[:,t] + hh . Whh[:,t]  (broadcast LDS reads)
        float g0 = bsum, g1 = 0.f, g2 = 0.f, g3 = 0.f;
        #pragma unroll
        for (int jq = 0; jq < 32; ++jq) {
            float4 v = qs4[jq];
            g0 = fmaf(v.x, wih[jq * 4 + 0], g0);
            g1 = fmaf(v.y, wih[jq * 4 + 1], g1);
            g2 = fmaf(v.z, wih[jq * 4 + 2], g2);
            g3 = fmaf(v.w, wih[jq * 4 + 3], g3);
        }
        #pragma unroll
        for (int jq = 0; jq < 16; ++jq) {
            float4 v = hh4[jq];
            g0 = fmaf(v.x, whh[jq * 4 + 0], g0);
            g1 = fmaf(v.y, whh[jq * 4 + 1], g1);
            g2 = fmaf(v.z, whh[jq * 4 + 2], g2);
            g3 = fmaf(v.w, whh[jq * 4 + 3], g3);
        }
        gates_l[t] = (g0 + g1) + (g2 + g3);
        __syncthreads();                                     // B1: gates ready
        if (t < 64) {
            float cn = sigf(gates_l[64 + t]) * ccr
                     + sigf(gates_l[t]) * tanhf(gates_l[128 + t]);
            ccr = cn;
            hh_l[t] = sigf(gates_l[192 + t]) * tanhf(cn);
        }
        __syncthreads();                                     // B2: hh ready
        // e[idx] = out_row . hh
        for (int idx = t; idx < cnt; idx += 256) {
            float s0a = 0.f, s1a = 0.f, s2a = 0.f, s3a = 0.f;
            if (idx < 192) {
                #pragma unroll
                for (int dq = 0; dq < 16; ++dq) {
                    float4 h = hh4[dq];
                    s0a = fmaf(cacheT[(dq * 4 + 0) * 193 + idx], h.x, s0a);
                    s1a = fmaf(cacheT[(dq * 4 + 1) * 193 + idx], h.y, s1a);
                    s2a = fmaf(cacheT[(dq * 4 + 2) * 193 + idx], h.z, s2a);
                    s3a = fmaf(cacheT[(dq * 4 + 3) * 193 + idx], h.w, s3a);
                }
            } else {
                const float* row = out + (size_t)(s0 + idx) * 64;
                #pragma unroll
                for (int dq = 0; dq < 16; ++dq) {
                    float4 h = hh4[dq];
                    s0a = fmaf(row[dq * 4 + 0], h.x, s0a);
                    s1a = fmaf(row[dq * 4 + 1], h.y, s1a);
                    s2a = fmaf(row[dq * 4 + 2], h.z, s2a);
                    s3a = fmaf(row[dq * 4 + 3], h.w, s3a);
                }
            }
            ebuf[idx] = (s0a + s1a) + (s2a + s3a);
        }
        __syncthreads();                                     // B3: e ready
        float lm = -3.0e38f;
        for (int idx = t; idx < cnt; idx += 256) lm = fmaxf(lm, ebuf[idx]);
        #pragma unroll
        for (int off = 32; off > 0; off >>= 1) lm = fmaxf(lm, __shfl_xor(lm, off, 64));
        if (lane == 0) redw[wave] = lm;
        __syncthreads();                                     // B4: wave maxes
        float m = fmaxf(fmaxf(redw[0], redw[1]), fmaxf(redw[2], redw[3]));
        float ls = 0.f;
        for (int idx = t; idx < cnt; idx += 256) {
            float a = __expf(ebuf[idx] - m);
            ebuf[idx] = a;
            ls += a;
        }
        #pragma unroll
        for (int off = 32; off > 0; off >>= 1) ls += __shfl_xor(ls, off, 64);
        if (lane == 0) redw2[wave] = ls;
        __syncthreads();                                     // B5: a's + wave sums
        float ssum = (redw2[0] + redw2[1]) + (redw2[2] + redw2[3]);
        float inv = (cnt > 0) ? 1.f / ssum : 0.f;
        // r[d=lane] = sum_row a[row]*node[row][d]; wave w handles rows w::4
        float r0 = 0.f;
        for (int row = wave; row < ccnt; row += 4)
            r0 = fmaf(ebuf[row], cacheT[lane * 193 + row], r0);
        for (int row = 192 + wave; row < cnt; row += 4)
            r0 = fmaf(ebuf[row], out[(size_t)(s0 + row) * 64 + lane], r0);
        redbuf[wave][lane] = r0;
        __syncthreads();                                     // B6: wave partials
        if (t < 64) {
            float s = ((redbuf[0][t] + redbuf[1][t]) + (redbuf[2][t] + redbuf[3][t]));
            qs[64 + t] = s * inv;
            qs[t] = hh_l[t];
        }
        __syncthreads();                                     // B7: qs ready
    }
    if (t < 64) {
        float s = pb0[t];
        #pragma unroll 4
        for (int k = 0; k < 128; ++k) s = fmaf(qs[k], pW0[k * 64 + t], s);
        tmp64[t] = fmaxf(s, 0.f);
    }
    __syncthreads();
    float h1v = 0.f;
    if (t < 64) {
        float s = pb1[t];
        #pragma unroll 4
        for (int k = 0; k < 64; ++k) s = fmaf(tmp64[k], pW1[k * 64 + t], s);
        h1v = fmaxf(s, 0.f);
    }
    __syncthreads();
    if (t < 64) tmp64[t] = h1v;
    __syncthreads();
    if (t < 64) {
        float s = pb2[t];
        #pragma unroll 4
        for (int k = 0; k < 64; ++k) s = fmaf(tmp64[k], pW2[k * 64 + t], s);
        gates_l[t] = fmaxf(s, 0.f) * pW3[t];
    }
    __syncthreads();
    if (t == 0) {
        float yy = pb3[0];
        for (int k = 0; k < 64; ++k) yy += gates_l[k];
        y[b] = yy;
    }
}

// ---------------- host ----------------

extern "C" void kernel_launch(void* const* d_in, const int* in_sizes, int n_in,
                              void* d_out, int out_size, void* d_ws, size_t ws_size,
                              hipStream_t stream) {
    const float* x         = (const float*)d_in[0];
    const float* edge_attr = (const float*)d_in[1];
    const int*   edge_idx  = (const int*)d_in[2];
    const int*   batch_map = (const int*)d_in[3];
    const float* pre_W0 = (const float*)d_in[4];
    const float* pre_b0 = (const float*)d_in[5];
    const float* pre_W1 = (const float*)d_in[6];
    const float* pre_b1 = (const float*)d_in[7];
    const float* pre_W2 = (const float*)d_in[8];
    const float* pre_b2 = (const float*)d_in[9];
    const float* enn_W1 = (const float*)d_in[10];
    const float* enn_b1 = (const float*)d_in[11];
    const float* enn_W2 = (const float*)d_in[12];
    const float* enn_b2 = (const float*)d_in[13];
    const float* root_W = (const float*)d_in[14];
    const float* conv_b = (const float*)d_in[15];
    const float* gru_Wih = (const float*)d_in[16];
    const float* gru_Whh = (const float*)d_in[17];
    const float* gru_bih = (const float*)d_in[18];
    const float* gru_bhh = (const float*)d_in[19];
    const float* s2s_Wih = (const float*)d_in[20];
    const float* s2s_Whh = (const float*)d_in[21];
    const float* s2s_bih = (const float*)d_in[22];
    const float* s2s_bhh = (const float*)d_in[23];
    const float* post_W0 = (const float*)d_in[24];
    const float* post_b0 = (const float*)d_in[25];
    const float* post_W1 = (const float*)d_in[26];
    const float* post_b1 = (const float*)d_in[27];
    const float* post_W2 = (const float*)d_in[28];
    const float* post_b2 = (const float*)d_in[29];
    const float* post_W3 = (const float*)d_in[30];
    const float* post_b3 = (const float*)d_in[31];
    float* yout = (float*)d_out;

    char* wp = (char*)d_ws;
    auto take = [&](size_t bytes) -> char* {
        char* r = wp;
        wp += (bytes + 255) & ~(size_t)255;
        return r;
    };
    float* outA = (float*)take((size_t)NN * 64 * 4);
    float* outB = (float*)take((size_t)NN * 64 * 4);
    float* agg  = (float*)take((size_t)NN * 64 * 4);
    __hip_bfloat16* W2F = (__hip_bfloat16*)take((size_t)3 * 64 * 4096 * 2);
    int* cnt_src  = (int*)take((size_t)NN * 4);
    int* cnt_dst  = (int*)take((size_t)NN * 4);
    int* csr_dst  = (int*)take((size_t)NN * BKT * 4);
    float* csr_ea = (float*)take((size_t)NN * BKT * 4);
    int* bstart   = (int*)take((size_t)NB * 4);
    int* bend     = (int*)take((size_t)NB * 4);

    k_setup<<<1248, 256, 0, stream>>>(x, pre_W0, pre_b0, pre_W1, pre_b1, pre_W2, pre_b2,
                                      enn_W2, W2F, outA, agg, cnt_src, cnt_dst,
                                      bstart, bend);
    k_bucket<<<128, 256, 0, stream>>>(edge_idx, edge_attr, batch_map, cnt_src, cnt_dst,
                                      csr_dst, csr_ea, bstart, bend);

    float* cur = outA;
    float* nxt = outB;
    for (int l = 0; l < 3; ++l) {
        k_fused<<<NN / 8, 256, 0, stream>>>(cur, W2F + (size_t)l * 64 * 4096,
                                            enn_b2 + (size_t)l * 4096,
                                            enn_W1 + l * 64, enn_b1 + l * 64,
                                            cnt_src, csr_dst, csr_ea, agg);
        k_gru<<<NN / 4, 256, 0, stream>>>(cur, agg, cnt_dst, root_W + l * 4096,
                                          conv_b + l * 64, gru_Wih + l * 64 * 192,
                                          gru_Whh + l * 64 * 192, gru_bih + l * 192,
                                          gru_bhh + l * 192, nxt);
        float* tmp = cur; cur = nxt; nxt = tmp;
    }
    k_s2s_post<<<NB, 256, 0, stream>>>(cur, bstart, bend, s2s_Wih, s2s_Whh, s2s_bih,
                                       s2s_bhh, post_W0, post_b0, post_W1, post_b1,
                                       post_W2, post_b2, post_W3, post_b3, yout);
}

// Round 5
// 354.311 us; speedup vs baseline: 1.0138x; 1.0138x over previous
//
#include <hip/hip_runtime.h>
#include <hip/hip_bf16.h>
#include <string.h>

#define NN   4096
#define NE   32768
#define NB   32
#define BKT  64   // per-src edge bucket capacity (deg ~ Poisson(8); P(>64) ~ 1e-30)
#define MSG_CHUNK 8

typedef __attribute__((ext_vector_type(8))) short short8;
typedef __attribute__((ext_vector_type(4))) float f4;

__device__ __forceinline__ float sigf(float x) { return 1.0f / (1.0f + __expf(-x)); }
__device__ __forceinline__ short f2bf(float f) {
    __hip_bfloat16 h = __float2bfloat16(f);
    short s;
    memcpy(&s, &h, sizeof(short));
    return s;
}

// ---------------- k_setup: init + W2->W2F fragment repack + pre-MLP ----------------
// blocks 0..31: zero counters, init batch ranges
// blocks 32..223: enn_W2[l][g][k][o] -> W2F fragment-packed bf16 (MFMA-ready)
//   per-g layout (4096 shorts): pos(o,k) = (o>>4)<<10 | (k>>5)<<9 | ((k>>3)&3)<<7 | (o&15)<<3 | (k&7)
//   so a B-fragment load is W2F_g + sub*1024 + half*512 + lane*8 (fully coalesced).
// blocks 224..1247: pre-MLP (4 nodes per block) + zero agg
__global__ __launch_bounds__(256) void k_setup(const float* __restrict__ x,
        const float* __restrict__ W0, const float* __restrict__ b0,
        const float* __restrict__ W1, const float* __restrict__ b1,
        const float* __restrict__ W2, const float* __restrict__ b2,
        const float* __restrict__ enn_W2, __hip_bfloat16* __restrict__ W2F,
        float* __restrict__ out, float* __restrict__ agg,
        int* cnt_src, int* cnt_dst, int* bstart, int* bend) {
    int bid = blockIdx.x, t = threadIdx.x;
    if (bid < 32) {
        int i = bid * 256 + t;
        if (i < NN) cnt_src[i] = 0;
        else cnt_dst[i - NN] = 0;
        if (i < NB) { bstart[i] = 0x7FFFFFFF; bend[i] = 0; }
    } else if (bid < 224) {
        __shared__ __hip_bfloat16 tile[4096];
        size_t base = (size_t)(bid - 32) * 4096;
        for (int i = t; i < 4096; i += 256) {
            int k = i >> 6, o = i & 63;
            int pos = ((o >> 4) << 10) | ((k >> 5) << 9) | (((k >> 3) & 3) << 7)
                    | ((o & 15) << 3) | (k & 7);
            tile[pos] = __float2bfloat16(enn_W2[base + i]);
        }
        __syncthreads();
        for (int i = t; i < 4096; i += 256) W2F[base + i] = tile[i];
    } else {
        __shared__ float xr[4][128], ha[4][64], hb[4][64];
        int w = t >> 6, j = t & 63;
        int n = (bid - 224) * 4 + w;
        xr[w][j] = x[(size_t)n * 128 + j];
        xr[w][64 + j] = x[(size_t)n * 128 + 64 + j];
        agg[(size_t)n * 64 + j] = 0.f;
        float s = b0[j];
        #pragma unroll 8
        for (int k = 0; k < 128; ++k) s = fmaf(xr[w][k], W0[k * 64 + j], s);
        ha[w][j] = fmaxf(s, 0.f);
        s = b1[j];
        #pragma unroll 8
        for (int k = 0; k < 64; ++k) s = fmaf(ha[w][k], W1[k * 64 + j], s);
        hb[w][j] = fmaxf(s, 0.f);
        s = b2[j];
        #pragma unroll 8
        for (int k = 0; k < 64; ++k) s = fmaf(hb[w][k], W2[k * 64 + j], s);
        out[(size_t)n * 64 + j] = fmaxf(s, 0.f);
    }
}

// ---------------- k_bucket: bucket CSR fill + batch ranges + S2S weight transpose ---
// blocks 0..127: edges; blocks 128..159: WihT/WhhT transpose (col-major copies so
// k_s2s_post's per-thread gate column is contiguous -> float4 loads, no reg arrays).
__global__ __launch_bounds__(256) void k_bucket(const int* __restrict__ eidx,
        const float* __restrict__ ea, const int* __restrict__ bm,
        const float* __restrict__ Wih, const float* __restrict__ Whh,
        float* __restrict__ WihT, float* __restrict__ WhhT,
        int* cnt_src, int* cnt_dst, int* csr_dst, float* csr_ea,
        int* bstart, int* bend) {
    int t = threadIdx.x;
    if (blockIdx.x >= 128) {
        int c0 = (blockIdx.x - 128) * 8;
        for (int i = t; i < 1024; i += 256) {
            int c = c0 + (i >> 7), j = i & 127;
            WihT[(size_t)c * 128 + j] = Wih[(size_t)j * 256 + c];
        }
        for (int i = t; i < 512; i += 256) {
            int c = c0 + (i >> 6), j = i & 63;
            WhhT[(size_t)c * 64 + j] = Whh[(size_t)j * 256 + c];
        }
        return;
    }
    int e = blockIdx.x * 256 + t;
    if (e < NE) {
        int s = eidx[e];
        int d = eidx[NE + e];
        int slot = atomicAdd(&cnt_src[s], 1);
        if (slot < BKT) {
            csr_dst[s * BKT + slot] = d;
            csr_ea[s * BKT + slot] = ea[e];
        }
        atomicAdd(&cnt_dst[d], 1);
    }
    if (e < NN) {
        int b = bm[e];
        atomicMin(&bstart[b], e);
        atomicMax(&bend[b], e + 1);
    }
}

// ---------------- k_fused: full-g P-tile MFMA in LDS + 1x-atomic message scatter ----
// One block = 8 src nodes, ALL 64 g (so each edge gets exactly ONE atomicAdd).
// LDS 74 KB -> 2 blocks/CU (8 waves/CU), grid 512 = exactly 2/CU, no tail.
// Phase 1: wave w computes P[n, g in [16w,16w+16), o] for all 8 nodes via MFMA
//   (A rows 8..15 duplicate nodes 0..7; quads 2,3 skip stores). Node region = 8 KB:
//   addr(n,g,o) = n*8192 + (g>>3)*1024 + o*16 + pair-dword, dword XOR'd by writer
//   quad for conflict-free ds_write (2 lanes/bank).
// Phase 2: wave w scatters messages for srcs {2w, 2w+1}; the quad-XOR is undone by
//   a wave-uniform dword swap keyed on the node's writer quad (nloc>>2).
__global__ __launch_bounds__(256, 2) void k_fused(const float* __restrict__ out,
        const __hip_bfloat16* __restrict__ W2F_l, const float* __restrict__ b2l,
        const float* __restrict__ W1l, const float* __restrict__ b1l,
        const int* __restrict__ cnt_src, const int* __restrict__ csr_dst,
        const float* __restrict__ csr_ea, float* __restrict__ agg) {
    __shared__ __hip_bfloat16 Pt[8 * 4096];           // 64 KB swizzled P tile
    __shared__ float outs[8][68];                     // fp32 node tile (padded)
    __shared__ float wlds[4][MSG_CHUNK][64];          // 8 KB We1 buffers (wave-private)
    int t = threadIdx.x, wave = t >> 6, lane = t & 63;
    int laneM = lane & 15, quad = lane >> 4;
    int n0 = blockIdx.x * 8;
    for (int i = t; i < 512; i += 256) outs[i >> 6][i & 63] = out[(size_t)n0 * 64 + i];
    __syncthreads();
    // A fragments (rows = 8 nodes, rows 8..15 duplicated; K = 64)
    short8 a0, a1;
    {
        const float* ar = &outs[laneM & 7][quad * 8];
        #pragma unroll
        for (int j = 0; j < 8; ++j) a0[j] = f2bf(ar[j]);
        const float* ar2 = &outs[laneM & 7][32 + quad * 8];
        #pragma unroll
        for (int j = 0; j < 8; ++j) a1[j] = f2bf(ar2[j]);
    }
    // BT (fp32, same summation order as the proven kernel): btr[u] = BT[n0+2*wave+u][lane]
    float btr[2] = {0.f, 0.f};
    for (int k = 0; k < 64; ++k) {
        float bv = b2l[k * 64 + lane];
        #pragma unroll
        for (int u = 0; u < 2; ++u) btr[u] = fmaf(outs[wave * 2 + u][k], bv, btr[u]);
    }
    // Phase 1: wave w owns g in [16w, 16w+16), as 8 adjacent pairs
    #pragma unroll 2
    for (int gp = 0; gp < 8; ++gp) {
        int gA = wave * 16 + gp * 2;                   // even g
        const __hip_bfloat16* BgA = W2F_l + (size_t)gA * 4096;
        const __hip_bfloat16* BgB = BgA + 4096;
        int c = gA >> 3;                               // g octet (0..7)
        int p = (gA >> 1) & 3;                         // pair-dword index in octet
        char* wb = (char*)Pt + (quad << 15) + (c << 10) + (laneM << 4)
                 + (((p ^ quad) & 3) << 2);
        #pragma unroll
        for (int sub = 0; sub < 4; ++sub) {
            short8 bA0 = *(const short8*)(BgA + sub * 1024 + lane * 8);
            short8 bA1 = *(const short8*)(BgA + sub * 1024 + 512 + lane * 8);
            short8 bB0 = *(const short8*)(BgB + sub * 1024 + lane * 8);
            short8 bB1 = *(const short8*)(BgB + sub * 1024 + 512 + lane * 8);
            f4 accA = {0.f, 0.f, 0.f, 0.f}, accB = {0.f, 0.f, 0.f, 0.f};
            accA = __builtin_amdgcn_mfma_f32_16x16x32_bf16(a0, bA0, accA, 0, 0, 0);
            accA = __builtin_amdgcn_mfma_f32_16x16x32_bf16(a1, bA1, accA, 0, 0, 0);
            accB = __builtin_amdgcn_mfma_f32_16x16x32_bf16(a0, bB0, accB, 0, 0, 0);
            accB = __builtin_amdgcn_mfma_f32_16x16x32_bf16(a1, bB1, accB, 0, 0, 0);
            if (quad < 2) {                            // nodes = quad*4+r in 0..7
                char* wbs = wb + (sub << 8);           // o += 16 -> 256 B
                #pragma unroll
                for (int r = 0; r < 4; ++r) {
                    unsigned pk = (unsigned)(unsigned short)f2bf(accA[r])
                                | ((unsigned)(unsigned short)f2bf(accB[r]) << 16);
                    *(unsigned*)(wbs + (r << 13)) = pk;    // node stride 8192 B
                }
            }
        }
    }
    __syncthreads();
    // Phase 2: full-g message scatter, 2 srcs per wave, one atomic per edge
    float w1v = W1l[lane], b1v = b1l[lane];
    for (int u = 0; u < 2; ++u) {
        int nloc = wave * 2 + u;
        int n = n0 + nloc;
        int deg = cnt_src[n];
        if (deg > BKT) deg = BKT;
        if (deg <= 0) continue;
        int wq = nloc >> 2;                            // writer quad (0 or 1)
        float preg[64];                                // P[n, g 0..63, o=lane]
        const char* Pn = (const char*)Pt + (nloc << 13);
        #pragma unroll
        for (int c = 0; c < 8; ++c) {
            uint4 vv = *(const uint4*)(Pn + (c << 10) + (lane << 4));
            unsigned d0 = vv.x, d1 = vv.y, d2 = vv.z, d3 = vv.w;
            if (wq & 1) { unsigned tt = d0; d0 = d1; d1 = tt; tt = d2; d2 = d3; d3 = tt; }
            union { unsigned u2; float f; } cv;
            cv.u2 = d0 << 16;          preg[c * 8 + 0] = cv.f;
            cv.u2 = d0 & 0xFFFF0000u;  preg[c * 8 + 1] = cv.f;
            cv.u2 = d1 << 16;          preg[c * 8 + 2] = cv.f;
            cv.u2 = d1 & 0xFFFF0000u;  preg[c * 8 + 3] = cv.f;
            cv.u2 = d2 << 16;          preg[c * 8 + 4] = cv.f;
            cv.u2 = d2 & 0xFFFF0000u;  preg[c * 8 + 5] = cv.f;
            cv.u2 = d3 << 16;          preg[c * 8 + 6] = cv.f;
            cv.u2 = d3 & 0xFFFF0000u;  preg[c * 8 + 7] = cv.f;
        }
        float bt = btr[u];
        const int* bdst = csr_dst + n * BKT;
        const float* bea = csr_ea + n * BKT;
        for (int c0 = 0; c0 < deg; c0 += MSG_CHUNK) {
            int cc = deg - c0;
            if (cc > MSG_CHUNK) cc = MSG_CHUNK;
            int dl = 0; float el = 0.f;
            if (lane < cc) { dl = bdst[c0 + lane]; el = bea[c0 + lane]; }
            for (int si = 0; si < cc; ++si) {
                float eav = __shfl(el, si, 64);
                wlds[wave][si][lane] = fmaxf(fmaf(eav, w1v, b1v), 0.f);   // We1 (lane = g)
            }
            for (int i = 0; i < cc; ++i) {
                int dst = __shfl(dl, i, 64);
                const float* wr = wlds[wave][i];
                float acc0 = bt, acc1 = 0.f, acc2 = 0.f, acc3 = 0.f;
                #pragma unroll
                for (int g = 0; g < 64; g += 16) {
                    float4 w0 = *(const float4*)(wr + g);
                    float4 w1 = *(const float4*)(wr + g + 4);
                    float4 w2 = *(const float4*)(wr + g + 8);
                    float4 w3 = *(const float4*)(wr + g + 12);
                    acc0 = fmaf(w0.x, preg[g], acc0);
                    acc0 = fmaf(w0.y, preg[g + 1], acc0);
                    acc0 = fmaf(w0.z, preg[g + 2], acc0);
                    acc0 = fmaf(w0.w, preg[g + 3], acc0);
                    acc1 = fmaf(w1.x, preg[g + 4], acc1);
                    acc1 = fmaf(w1.y, preg[g + 5], acc1);
                    acc1 = fmaf(w1.z, preg[g + 6], acc1);
                    acc1 = fmaf(w1.w, preg[g + 7], acc1);
                    acc2 = fmaf(w2.x, preg[g + 8], acc2);
                    acc2 = fmaf(w2.y, preg[g + 9], acc2);
                    acc2 = fmaf(w2.z, preg[g + 10], acc2);
                    acc2 = fmaf(w2.w, preg[g + 11], acc2);
                    acc3 = fmaf(w3.x, preg[g + 12], acc3);
                    acc3 = fmaf(w3.y, preg[g + 13], acc3);
                    acc3 = fmaf(w3.z, preg[g + 14], acc3);
                    acc3 = fmaf(w3.w, preg[g + 15], acc3);
                }
                float acc = (acc0 + acc1) + (acc2 + acc3);
                atomicAdd(&agg[(size_t)dst * 64 + lane], acc);   // un-normalized; /deg in GRU
            }
        }
    }
}

// ---------------- k_gru: conv (+deg-normalize) + GRU (+ agg re-zero) ----------------
__global__ __launch_bounds__(256) void k_gru(const float* __restrict__ out,
        float* __restrict__ agg, const int* __restrict__ cnt_dst,
        const float* __restrict__ rootW, const float* __restrict__ convb,
        const float* __restrict__ Wih, const float* __restrict__ Whh,
        const float* __restrict__ bih, const float* __restrict__ bhh,
        float* __restrict__ outn) {
    __shared__ float sh[4][64], sc[4][64];
    int t = threadIdx.x, w = t >> 6, j = t & 63;
    int n = blockIdx.x * 4 + w;
    float hj = out[(size_t)n * 64 + j];
    sh[w][j] = hj;
    int dg = cnt_dst[n];
    float invd = 1.0f / (float)(dg > 0 ? dg : 1);
    float av = agg[(size_t)n * 64 + j];
    agg[(size_t)n * 64 + j] = 0.f;          // pre-zero for next layer's atomics
    __syncthreads();
    float s = av * invd + convb[j];
    #pragma unroll 8
    for (int k = 0; k < 64; ++k) s = fmaf(sh[w][k], rootW[k * 64 + j], s);
    float conv = fmaxf(s, 0.f);
    sc[w][j] = conv;
    __syncthreads();
    float gir = bih[j], giz = bih[64 + j], gin = bih[128 + j];
    float ghr = bhh[j], ghz = bhh[64 + j], ghn = bhh[128 + j];
    #pragma unroll 4
    for (int k = 0; k < 64; ++k) {
        float c = sc[w][k], h = sh[w][k];
        gir = fmaf(c, Wih[k * 192 + j], gir);
        giz = fmaf(c, Wih[k * 192 + 64 + j], giz);
        gin = fmaf(c, Wih[k * 192 + 128 + j], gin);
        ghr = fmaf(h, Whh[k * 192 + j], ghr);
        ghz = fmaf(h, Whh[k * 192 + 64 + j], ghz);
        ghn = fmaf(h, Whh[k * 192 + 128 + j], ghn);
    }
    float r = sigf(gir + ghr);
    float z = sigf(giz + ghz);
    float nn = tanhf(gin + r * ghn);
    outn[(size_t)n * 64 + j] = (1.f - z) * nn + z * hj;
}

// ---------------- Set2Set (3 steps) + post-MLP: no-spill 256-thread version --------
// One block = one batch. Thread t owns gate column t; its weight column lives in
// TRANSPOSED global copies (WihT/WhhT, prepared by k_bucket) and is re-read each
// step as 32+16 independent float4 loads (L2/L3-hot, all in flight) -- no register
// arrays, no scratch spill (the R4 164-VGPR version spilled its 192-float arrays).
// cacheT[64][193]: conflict-free in both read directions. 7 barriers/step, 4 waves.
__global__ __launch_bounds__(256, 1) void k_s2s_post(const float* __restrict__ out,
        const int* __restrict__ bstart, const int* __restrict__ bend,
        const float* __restrict__ WihT, const float* __restrict__ WhhT,
        const float* __restrict__ bih, const float* __restrict__ bhh,
        const float* __restrict__ pW0, const float* __restrict__ pb0,
        const float* __restrict__ pW1, const float* __restrict__ pb1,
        const float* __restrict__ pW2, const float* __restrict__ pb2,
        const float* __restrict__ pW3, const float* __restrict__ pb3,
        float* __restrict__ y) {
    __shared__ float cacheT[64 * 193];     // transposed node tile (49.4 KB)
    __shared__ float qs[128];              // [0:64]=q(hh), [64:128]=r_read
    __shared__ float hh_l[64];
    __shared__ float gates_l[256];
    __shared__ float ebuf[1024];
    __shared__ float redw[4], redw2[4];
    __shared__ float redbuf[4][64];
    __shared__ float tmp64[64];
    int t = threadIdx.x, wave = t >> 6, lane = t & 63;
    int b = blockIdx.x;
    int s0 = bstart[b], e0 = bend[b];
    int cnt = e0 - s0;
    if (cnt < 0) cnt = 0;
    if (cnt > 1024) cnt = 1024;
    int ccnt = cnt < 192 ? cnt : 192;
    // fill cacheT[d][row] from out rows (coalesced reads; writes bank (d+row)%32)
    for (int i = t; i < ccnt * 64; i += 256) {
        int row = i >> 6, d = i & 63;
        cacheT[d * 193 + row] = out[(size_t)(s0 + row) * 64 + d];
    }
    const float4* wihT4 = (const float4*)(WihT + (size_t)t * 128);
    const float4* whhT4 = (const float4*)(WhhT + (size_t)t * 64);
    float bsum = bih[t] + bhh[t];
    float ccr = 0.f;                       // cc for dim t (threads t<64 only)
    if (t < 128) qs[t] = 0.f;
    if (t < 64) hh_l[t] = 0.f;
    __syncthreads();
    const float4* qs4 = (const float4*)qs;
    const float4* hh4 = (const float4*)hh_l;
    for (int step = 0; step < 3; ++step) {
        // gates[t] = bias + qs . Wih[:,t] + hh . Whh[:,t]
        // weight float4 loads are independent & contiguous per thread (L2-hot)
        float g0 = bsum, g1 = 0.f, g2 = 0.f, g3 = 0.f;
        #pragma unroll
        for (int jq = 0; jq < 32; ++jq) {
            float4 w = wihT4[jq];
            float4 v = qs4[jq];
            g0 = fmaf(v.x, w.x, g0);
            g1 = fmaf(v.y, w.y, g1);
            g2 = fmaf(v.z, w.z, g2);
            g3 = fmaf(v.w, w.w, g3);
        }
        #pragma unroll
        for (int jq = 0; jq < 16; ++jq) {
            float4 w = whhT4[jq];
            float4 v = hh4[jq];
            g0 = fmaf(v.x, w.x, g0);
            g1 = fmaf(v.y, w.y, g1);
            g2 = fmaf(v.z, w.z, g2);
            g3 = fmaf(v.w, w.w, g3);
        }
        gates_l[t] = (g0 + g1) + (g2 + g3);
        __syncthreads();                                     // B1: gates ready
        if (t < 64) {
            float cn = sigf(gates_l[64 + t]) * ccr
                     + sigf(gates_l[t]) * tanhf(gates_l[128 + t]);
            ccr = cn;
            hh_l[t] = sigf(gates_l[192 + t]) * tanhf(cn);
        }
        __syncthreads();                                     // B2: hh ready
        // e[idx] = out_row . hh
        for (int idx = t; idx < cnt; idx += 256) {
            float s0a = 0.f, s1a = 0.f, s2a = 0.f, s3a = 0.f;
            if (idx < 192) {
                #pragma unroll
                for (int dq = 0; dq < 16; ++dq) {
                    float4 h = hh4[dq];
                    s0a = fmaf(cacheT[(dq * 4 + 0) * 193 + idx], h.x, s0a);
                    s1a = fmaf(cacheT[(dq * 4 + 1) * 193 + idx], h.y, s1a);
                    s2a = fmaf(cacheT[(dq * 4 + 2) * 193 + idx], h.z, s2a);
                    s3a = fmaf(cacheT[(dq * 4 + 3) * 193 + idx], h.w, s3a);
                }
            } else {
                const float* row = out + (size_t)(s0 + idx) * 64;
                #pragma unroll
                for (int dq = 0; dq < 16; ++dq) {
                    float4 h = hh4[dq];
                    s0a = fmaf(row[dq * 4 + 0], h.x, s0a);
                    s1a = fmaf(row[dq * 4 + 1], h.y, s1a);
                    s2a = fmaf(row[dq * 4 + 2], h.z, s2a);
                    s3a = fmaf(row[dq * 4 + 3], h.w, s3a);
                }
            }
            ebuf[idx] = (s0a + s1a) + (s2a + s3a);
        }
        __syncthreads();                                     // B3: e ready
        float lm = -3.0e38f;
        for (int idx = t; idx < cnt; idx += 256) lm = fmaxf(lm, ebuf[idx]);
        #pragma unroll
        for (int off = 32; off > 0; off >>= 1) lm = fmaxf(lm, __shfl_xor(lm, off, 64));
        if (lane == 0) redw[wave] = lm;
        __syncthreads();                                     // B4: wave maxes
        float m = fmaxf(fmaxf(redw[0], redw[1]), fmaxf(redw[2], redw[3]));
        float ls = 0.f;
        for (int idx = t; idx < cnt; idx += 256) {
            float a = __expf(ebuf[idx] - m);
            ebuf[idx] = a;
            ls += a;
        }
        #pragma unroll
        for (int off = 32; off > 0; off >>= 1) ls += __shfl_xor(ls, off, 64);
        if (lane == 0) redw2[wave] = ls;
        __syncthreads();                                     // B5: a's + wave sums
        float ssum = (redw2[0] + redw2[1]) + (redw2[2] + redw2[3]);
        float inv = (cnt > 0) ? 1.f / ssum : 0.f;
        // r[d=lane] = sum_row a[row]*node[row][d]; wave w handles rows w::4
        float r0 = 0.f;
        for (int row = wave; row < ccnt; row += 4)
            r0 = fmaf(ebuf[row], cacheT[lane * 193 + row], r0);
        for (int row = 192 + wave; row < cnt; row += 4)
            r0 = fmaf(ebuf[row], out[(size_t)(s0 + row) * 64 + lane], r0);
        redbuf[wave][lane] = r0;
        __syncthreads();                                     // B6: wave partials
        if (t < 64) {
            float s = ((redbuf[0][t] + redbuf[1][t]) + (redbuf[2][t] + redbuf[3][t]));
            qs[64 + t] = s * inv;
            qs[t] = hh_l[t];
        }
        __syncthreads();                                     // B7: qs ready
    }
    if (t < 64) {
        float s = pb0[t];
        #pragma unroll 4
        for (int k = 0; k < 128; ++k) s = fmaf(qs[k], pW0[k * 64 + t], s);
        tmp64[t] = fmaxf(s, 0.f);
    }
    __syncthreads();
    float h1v = 0.f;
    if (t < 64) {
        float s = pb1[t];
        #pragma unroll 4
        for (int k = 0; k < 64; ++k) s = fmaf(tmp64[k], pW1[k * 64 + t], s);
        h1v = fmaxf(s, 0.f);
    }
    __syncthreads();
    if (t < 64) tmp64[t] = h1v;
    __syncthreads();
    if (t < 64) {
        float s = pb2[t];
        #pragma unroll 4
        for (int k = 0; k < 64; ++k) s = fmaf(tmp64[k], pW2[k * 64 + t], s);
        gates_l[t] = fmaxf(s, 0.f) * pW3[t];
    }
    __syncthreads();
    if (t == 0) {
        float yy = pb3[0];
        for (int k = 0; k < 64; ++k) yy += gates_l[k];
        y[b] = yy;
    }
}

// ---------------- host ----------------

extern "C" void kernel_launch(void* const* d_in, const int* in_sizes, int n_in,
                              void* d_out, int out_size, void* d_ws, size_t ws_size,
                              hipStream_t stream) {
    const float* x         = (const float*)d_in[0];
    const float* edge_attr = (const float*)d_in[1];
    const int*   edge_idx  = (const int*)d_in[2];
    const int*   batch_map = (const int*)d_in[3];
    const float* pre_W0 = (const float*)d_in[4];
    const float* pre_b0 = (const float*)d_in[5];
    const float* pre_W1 = (const float*)d_in[6];
    const float* pre_b1 = (const float*)d_in[7];
    const float* pre_W2 = (const float*)d_in[8];
    const float* pre_b2 = (const float*)d_in[9];
    const float* enn_W1 = (const float*)d_in[10];
    const float* enn_b1 = (const float*)d_in[11];
    const float* enn_W2 = (const float*)d_in[12];
    const float* enn_b2 = (const float*)d_in[13];
    const float* root_W = (const float*)d_in[14];
    const float* conv_b = (const float*)d_in[15];
    const float* gru_Wih = (const float*)d_in[16];
    const float* gru_Whh = (const float*)d_in[17];
    const float* gru_bih = (const float*)d_in[18];
    const float* gru_bhh = (const float*)d_in[19];
    const float* s2s_Wih = (const float*)d_in[20];
    const float* s2s_Whh = (const float*)d_in[21];
    const float* s2s_bih = (const float*)d_in[22];
    const float* s2s_bhh = (const float*)d_in[23];
    const float* post_W0 = (const float*)d_in[24];
    const float* post_b0 = (const float*)d_in[25];
    const float* post_W1 = (const float*)d_in[26];
    const float* post_b1 = (const float*)d_in[27];
    const float* post_W2 = (const float*)d_in[28];
    const float* post_b2 = (const float*)d_in[29];
    const float* post_W3 = (const float*)d_in[30];
    const float* post_b3 = (const float*)d_in[31];
    float* yout = (float*)d_out;

    char* wp = (char*)d_ws;
    auto take = [&](size_t bytes) -> char* {
        char* r = wp;
        wp += (bytes + 255) & ~(size_t)255;
        return r;
    };
    float* outA = (float*)take((size_t)NN * 64 * 4);
    float* outB = (float*)take((size_t)NN * 64 * 4);
    float* agg  = (float*)take((size_t)NN * 64 * 4);
    __hip_bfloat16* W2F = (__hip_bfloat16*)take((size_t)3 * 64 * 4096 * 2);
    int* cnt_src  = (int*)take((size_t)NN * 4);
    int* cnt_dst  = (int*)take((size_t)NN * 4);
    int* csr_dst  = (int*)take((size_t)NN * BKT * 4);
    float* csr_ea = (float*)take((size_t)NN * BKT * 4);
    int* bstart   = (int*)take((size_t)NB * 4);
    int* bend     = (int*)take((size_t)NB * 4);
    float* WihT   = (float*)take((size_t)256 * 128 * 4);
    float* WhhT   = (float*)take((size_t)256 * 64 * 4);

    k_setup<<<1248, 256, 0, stream>>>(x, pre_W0, pre_b0, pre_W1, pre_b1, pre_W2, pre_b2,
                                      enn_W2, W2F, outA, agg, cnt_src, cnt_dst,
                                      bstart, bend);
    k_bucket<<<160, 256, 0, stream>>>(edge_idx, edge_attr, batch_map,
                                      s2s_Wih, s2s_Whh, WihT, WhhT,
                                      cnt_src, cnt_dst, csr_dst, csr_ea, bstart, bend);

    float* cur = outA;
    float* nxt = outB;
    for (int l = 0; l < 3; ++l) {
        k_fused<<<NN / 8, 256, 0, stream>>>(cur, W2F + (size_t)l * 64 * 4096,
                                            enn_b2 + (size_t)l * 4096,
                                            enn_W1 + l * 64, enn_b1 + l * 64,
                                            cnt_src, csr_dst, csr_ea, agg);
        k_gru<<<NN / 4, 256, 0, stream>>>(cur, agg, cnt_dst, root_W + l * 4096,
                                          conv_b + l * 64, gru_Wih + l * 64 * 192,
                                          gru_Whh + l * 64 * 192, gru_bih + l * 192,
                                          gru_bhh + l * 192, nxt);
        float* tmp = cur; cur = nxt; nxt = tmp;
    }
    k_s2s_post<<<NB, 256, 0, stream>>>(cur, bstart, bend, WihT, WhhT, s2s_bih,
                                       s2s_bhh, post_W0, post_b0, post_W1, post_b1,
                                       post_W2, post_b2, post_W3, post_b3, yout);
}

// Round 6
// 348.768 us; speedup vs baseline: 1.0299x; 1.0159x over previous
//
#include <hip/hip_runtime.h>
#include <hip/hip_bf16.h>
#include <string.h>

#define NN   4096
#define NE   32768
#define NB   32
#define BKT  64   // per-src edge bucket capacity (deg ~ Poisson(8); P(>64) ~ 1e-30)
#define MSG_CHUNK 8

typedef __attribute__((ext_vector_type(8))) short short8;
typedef __attribute__((ext_vector_type(4))) float f4;

__device__ __forceinline__ float sigf(float x) { return 1.0f / (1.0f + __expf(-x)); }
__device__ __forceinline__ short f2bf(float f) {
    __hip_bfloat16 h = __float2bfloat16(f);
    short s;
    memcpy(&s, &h, sizeof(short));
    return s;
}

// ---------------- k_setup: init + W2->W2F fragment repack + pre-MLP ----------------
__global__ __launch_bounds__(256) void k_setup(const float* __restrict__ x,
        const float* __restrict__ W0, const float* __restrict__ b0,
        const float* __restrict__ W1, const float* __restrict__ b1,
        const float* __restrict__ W2, const float* __restrict__ b2,
        const float* __restrict__ enn_W2, __hip_bfloat16* __restrict__ W2F,
        float* __restrict__ out, float* __restrict__ agg,
        int* cnt_src, int* cnt_dst, int* bstart, int* bend) {
    int bid = blockIdx.x, t = threadIdx.x;
    if (bid < 32) {
        int i = bid * 256 + t;
        if (i < NN) cnt_src[i] = 0;
        else cnt_dst[i - NN] = 0;
        if (i < NB) { bstart[i] = 0x7FFFFFFF; bend[i] = 0; }
    } else if (bid < 224) {
        __shared__ __hip_bfloat16 tile[4096];
        size_t base = (size_t)(bid - 32) * 4096;
        for (int i = t; i < 4096; i += 256) {
            int k = i >> 6, o = i & 63;
            int pos = ((o >> 4) << 10) | ((k >> 5) << 9) | (((k >> 3) & 3) << 7)
                    | ((o & 15) << 3) | (k & 7);
            tile[pos] = __float2bfloat16(enn_W2[base + i]);
        }
        __syncthreads();
        for (int i = t; i < 4096; i += 256) W2F[base + i] = tile[i];
    } else {
        __shared__ float xr[4][128], ha[4][64], hb[4][64];
        int w = t >> 6, j = t & 63;
        int n = (bid - 224) * 4 + w;
        xr[w][j] = x[(size_t)n * 128 + j];
        xr[w][64 + j] = x[(size_t)n * 128 + 64 + j];
        agg[(size_t)n * 64 + j] = 0.f;
        float s = b0[j];
        #pragma unroll 8
        for (int k = 0; k < 128; ++k) s = fmaf(xr[w][k], W0[k * 64 + j], s);
        ha[w][j] = fmaxf(s, 0.f);
        s = b1[j];
        #pragma unroll 8
        for (int k = 0; k < 64; ++k) s = fmaf(ha[w][k], W1[k * 64 + j], s);
        hb[w][j] = fmaxf(s, 0.f);
        s = b2[j];
        #pragma unroll 8
        for (int k = 0; k < 64; ++k) s = fmaf(hb[w][k], W2[k * 64 + j], s);
        out[(size_t)n * 64 + j] = fmaxf(s, 0.f);
    }
}

// ---------------- k_bucket: bucket CSR fill + batch ranges + S2S weight transpose ---
__global__ __launch_bounds__(256) void k_bucket(const int* __restrict__ eidx,
        const float* __restrict__ ea, const int* __restrict__ bm,
        const float* __restrict__ Wih, const float* __restrict__ Whh,
        float* __restrict__ WihT, float* __restrict__ WhhT,
        int* cnt_src, int* cnt_dst, int* csr_dst, float* csr_ea,
        int* bstart, int* bend) {
    int t = threadIdx.x;
    if (blockIdx.x >= 128) {
        int c0 = (blockIdx.x - 128) * 8;
        for (int i = t; i < 1024; i += 256) {
            int c = c0 + (i >> 7), j = i & 127;
            WihT[(size_t)c * 128 + j] = Wih[(size_t)j * 256 + c];
        }
        for (int i = t; i < 512; i += 256) {
            int c = c0 + (i >> 6), j = i & 63;
            WhhT[(size_t)c * 64 + j] = Whh[(size_t)j * 256 + c];
        }
        return;
    }
    int e = blockIdx.x * 256 + t;
    if (e < NE) {
        int s = eidx[e];
        int d = eidx[NE + e];
        int slot = atomicAdd(&cnt_src[s], 1);
        if (slot < BKT) {
            csr_dst[s * BKT + slot] = d;
            csr_ea[s * BKT + slot] = ea[e];
        }
        atomicAdd(&cnt_dst[d], 1);
    }
    if (e < NN) {
        int b = bm[e];
        atomicMin(&bstart[b], e);
        atomicMax(&bend[b], e + 1);
    }
}

// ---------------- k_fused: full-g P-tile MFMA in LDS + 1x-atomic message scatter ----
__global__ __launch_bounds__(256, 2) void k_fused(const float* __restrict__ out,
        const __hip_bfloat16* __restrict__ W2F_l, const float* __restrict__ b2l,
        const float* __restrict__ W1l, const float* __restrict__ b1l,
        const int* __restrict__ cnt_src, const int* __restrict__ csr_dst,
        const float* __restrict__ csr_ea, float* __restrict__ agg) {
    __shared__ __hip_bfloat16 Pt[8 * 4096];           // 64 KB swizzled P tile
    __shared__ float outs[8][68];                     // fp32 node tile (padded)
    __shared__ float wlds[4][MSG_CHUNK][64];          // 8 KB We1 buffers (wave-private)
    int t = threadIdx.x, wave = t >> 6, lane = t & 63;
    int laneM = lane & 15, quad = lane >> 4;
    int n0 = blockIdx.x * 8;
    for (int i = t; i < 512; i += 256) outs[i >> 6][i & 63] = out[(size_t)n0 * 64 + i];
    __syncthreads();
    // A fragments (rows = 8 nodes, rows 8..15 duplicated; K = 64)
    short8 a0, a1;
    {
        const float* ar = &outs[laneM & 7][quad * 8];
        #pragma unroll
        for (int j = 0; j < 8; ++j) a0[j] = f2bf(ar[j]);
        const float* ar2 = &outs[laneM & 7][32 + quad * 8];
        #pragma unroll
        for (int j = 0; j < 8; ++j) a1[j] = f2bf(ar2[j]);
    }
    // BT (fp32, same summation order as the proven kernel)
    float btr[2] = {0.f, 0.f};
    for (int k = 0; k < 64; ++k) {
        float bv = b2l[k * 64 + lane];
        #pragma unroll
        for (int u = 0; u < 2; ++u) btr[u] = fmaf(outs[wave * 2 + u][k], bv, btr[u]);
    }
    // Phase 1: wave w owns g in [16w, 16w+16), as 8 adjacent pairs
    #pragma unroll 2
    for (int gp = 0; gp < 8; ++gp) {
        int gA = wave * 16 + gp * 2;                   // even g
        const __hip_bfloat16* BgA = W2F_l + (size_t)gA * 4096;
        const __hip_bfloat16* BgB = BgA + 4096;
        int c = gA >> 3;                               // g octet (0..7)
        int p = (gA >> 1) & 3;                         // pair-dword index in octet
        char* wb = (char*)Pt + (quad << 15) + (c << 10) + (laneM << 4)
                 + (((p ^ quad) & 3) << 2);
        #pragma unroll
        for (int sub = 0; sub < 4; ++sub) {
            short8 bA0 = *(const short8*)(BgA + sub * 1024 + lane * 8);
            short8 bA1 = *(const short8*)(BgA + sub * 1024 + 512 + lane * 8);
            short8 bB0 = *(const short8*)(BgB + sub * 1024 + lane * 8);
            short8 bB1 = *(const short8*)(BgB + sub * 1024 + 512 + lane * 8);
            f4 accA = {0.f, 0.f, 0.f, 0.f}, accB = {0.f, 0.f, 0.f, 0.f};
            accA = __builtin_amdgcn_mfma_f32_16x16x32_bf16(a0, bA0, accA, 0, 0, 0);
            accA = __builtin_amdgcn_mfma_f32_16x16x32_bf16(a1, bA1, accA, 0, 0, 0);
            accB = __builtin_amdgcn_mfma_f32_16x16x32_bf16(a0, bB0, accB, 0, 0, 0);
            accB = __builtin_amdgcn_mfma_f32_16x16x32_bf16(a1, bB1, accB, 0, 0, 0);
            if (quad < 2) {                            // nodes = quad*4+r in 0..7
                char* wbs = wb + (sub << 8);           // o += 16 -> 256 B
                #pragma unroll
                for (int r = 0; r < 4; ++r) {
                    unsigned pk = (unsigned)(unsigned short)f2bf(accA[r])
                                | ((unsigned)(unsigned short)f2bf(accB[r]) << 16);
                    *(unsigned*)(wbs + (r << 13)) = pk;    // node stride 8192 B
                }
            }
        }
    }
    __syncthreads();
    // Phase 2: full-g message scatter, 2 srcs per wave, one atomic per edge
    float w1v = W1l[lane], b1v = b1l[lane];
    for (int u = 0; u < 2; ++u) {
        int nloc = wave * 2 + u;
        int n = n0 + nloc;
        int deg = cnt_src[n];
        if (deg > BKT) deg = BKT;
        if (deg <= 0) continue;
        int wq = nloc >> 2;                            // writer quad (0 or 1)
        float preg[64];                                // P[n, g 0..63, o=lane]
        const char* Pn = (const char*)Pt + (nloc << 13);
        #pragma unroll
        for (int c = 0; c < 8; ++c) {
            uint4 vv = *(const uint4*)(Pn + (c << 10) + (lane << 4));
            unsigned d0 = vv.x, d1 = vv.y, d2 = vv.z, d3 = vv.w;
            if (wq & 1) { unsigned tt = d0; d0 = d1; d1 = tt; tt = d2; d2 = d3; d3 = tt; }
            union { unsigned u2; float f; } cv;
            cv.u2 = d0 << 16;          preg[c * 8 + 0] = cv.f;
            cv.u2 = d0 & 0xFFFF0000u;  preg[c * 8 + 1] = cv.f;
            cv.u2 = d1 << 16;          preg[c * 8 + 2] = cv.f;
            cv.u2 = d1 & 0xFFFF0000u;  preg[c * 8 + 3] = cv.f;
            cv.u2 = d2 << 16;          preg[c * 8 + 4] = cv.f;
            cv.u2 = d2 & 0xFFFF0000u;  preg[c * 8 + 5] = cv.f;
            cv.u2 = d3 << 16;          preg[c * 8 + 6] = cv.f;
            cv.u2 = d3 & 0xFFFF0000u;  preg[c * 8 + 7] = cv.f;
        }
        float bt = btr[u];
        const int* bdst = csr_dst + n * BKT;
        const float* bea = csr_ea + n * BKT;
        for (int c0 = 0; c0 < deg; c0 += MSG_CHUNK) {
            int cc = deg - c0;
            if (cc > MSG_CHUNK) cc = MSG_CHUNK;
            int dl = 0; float el = 0.f;
            if (lane < cc) { dl = bdst[c0 + lane]; el = bea[c0 + lane]; }
            for (int si = 0; si < cc; ++si) {
                float eav = __shfl(el, si, 64);
                wlds[wave][si][lane] = fmaxf(fmaf(eav, w1v, b1v), 0.f);   // We1 (lane = g)
            }
            for (int i = 0; i < cc; ++i) {
                int dst = __shfl(dl, i, 64);
                const float* wr = wlds[wave][i];
                float acc0 = bt, acc1 = 0.f, acc2 = 0.f, acc3 = 0.f;
                #pragma unroll
                for (int g = 0; g < 64; g += 16) {
                    float4 w0 = *(const float4*)(wr + g);
                    float4 w1 = *(const float4*)(wr + g + 4);
                    float4 w2 = *(const float4*)(wr + g + 8);
                    float4 w3 = *(const float4*)(wr + g + 12);
                    acc0 = fmaf(w0.x, preg[g], acc0);
                    acc0 = fmaf(w0.y, preg[g + 1], acc0);
                    acc0 = fmaf(w0.z, preg[g + 2], acc0);
                    acc0 = fmaf(w0.w, preg[g + 3], acc0);
                    acc1 = fmaf(w1.x, preg[g + 4], acc1);
                    acc1 = fmaf(w1.y, preg[g + 5], acc1);
                    acc1 = fmaf(w1.z, preg[g + 6], acc1);
                    acc1 = fmaf(w1.w, preg[g + 7], acc1);
                    acc2 = fmaf(w2.x, preg[g + 8], acc2);
                    acc2 = fmaf(w2.y, preg[g + 9], acc2);
                    acc2 = fmaf(w2.z, preg[g + 10], acc2);
                    acc2 = fmaf(w2.w, preg[g + 11], acc2);
                    acc3 = fmaf(w3.x, preg[g + 12], acc3);
                    acc3 = fmaf(w3.y, preg[g + 13], acc3);
                    acc3 = fmaf(w3.z, preg[g + 14], acc3);
                    acc3 = fmaf(w3.w, preg[g + 15], acc3);
                }
                float acc = (acc0 + acc1) + (acc2 + acc3);
                atomicAdd(&agg[(size_t)dst * 64 + lane], acc);   // un-normalized; /deg in GRU
            }
        }
    }
}

// ---------------- k_gru: conv (+deg-normalize) + GRU (+ agg re-zero) ----------------
__global__ __launch_bounds__(256) void k_gru(const float* __restrict__ out,
        float* __restrict__ agg, const int* __restrict__ cnt_dst,
        const float* __restrict__ rootW, const float* __restrict__ convb,
        const float* __restrict__ Wih, const float* __restrict__ Whh,
        const float* __restrict__ bih, const float* __restrict__ bhh,
        float* __restrict__ outn) {
    __shared__ float sh[4][64], sc[4][64];
    int t = threadIdx.x, w = t >> 6, j = t & 63;
    int n = blockIdx.x * 4 + w;
    float hj = out[(size_t)n * 64 + j];
    sh[w][j] = hj;
    int dg = cnt_dst[n];
    float invd = 1.0f / (float)(dg > 0 ? dg : 1);
    float av = agg[(size_t)n * 64 + j];
    agg[(size_t)n * 64 + j] = 0.f;          // pre-zero for next layer's atomics
    __syncthreads();
    float s = av * invd + convb[j];
    #pragma unroll 8
    for (int k = 0; k < 64; ++k) s = fmaf(sh[w][k], rootW[k * 64 + j], s);
    float conv = fmaxf(s, 0.f);
    sc[w][j] = conv;
    __syncthreads();
    float gir = bih[j], giz = bih[64 + j], gin = bih[128 + j];
    float ghr = bhh[j], ghz = bhh[64 + j], ghn = bhh[128 + j];
    #pragma unroll 4
    for (int k = 0; k < 64; ++k) {
        float c = sc[w][k], h = sh[w][k];
        gir = fmaf(c, Wih[k * 192 + j], gir);
        giz = fmaf(c, Wih[k * 192 + 64 + j], giz);
        gin = fmaf(c, Wih[k * 192 + 128 + j], gin);
        ghr = fmaf(h, Whh[k * 192 + j], ghr);
        ghz = fmaf(h, Whh[k * 192 + 64 + j], ghz);
        ghn = fmaf(h, Whh[k * 192 + 128 + j], ghn);
    }
    float r = sigf(gir + ghr);
    float z = sigf(giz + ghz);
    float nn = tanhf(gin + r * ghn);
    outn[(size_t)n * 64 + j] = (1.f - z) * nn + z * hj;
}

// ---------------- Set2Set (3 steps) + post-MLP: burst-latency version ---------------
// The three prior rewrites all landed at ~42 us because the block's critical path is
// ~100 SERIALIZED memory-latency round trips (staging loop: 32 load->wait->ds_write
// iterations; post-MLP: ~64 waits on scalar/4-unrolled weight loads), not barriers or
// spills. This version batches them: (a) node tile staged via 12 guarded float4 loads
// issued before any LDS write (1 trip); (b) ALL post-MLP weights burst-copied to LDS
// at kernel start (1-2 trips), post-MLP reads LDS only. Math order unchanged.
__global__ __launch_bounds__(256, 1) void k_s2s_post(const float* __restrict__ out,
        const int* __restrict__ bstart, const int* __restrict__ bend,
        const float* __restrict__ WihT, const float* __restrict__ WhhT,
        const float* __restrict__ bih, const float* __restrict__ bhh,
        const float* __restrict__ pW0, const float* __restrict__ pb0,
        const float* __restrict__ pW1, const float* __restrict__ pb1,
        const float* __restrict__ pW2, const float* __restrict__ pb2,
        const float* __restrict__ pW3, const float* __restrict__ pb3,
        float* __restrict__ y) {
    __shared__ float cacheT[64 * 193];     // transposed node tile (49.4 KB)
    __shared__ float wpost[16448];         // pW0|pW1|pW2|pW3 (64.3 KB)
    __shared__ float qs[128];              // [0:64]=q(hh), [64:128]=r_read
    __shared__ float hh_l[64];
    __shared__ float gates_l[256];
    __shared__ float ebuf[1024];
    __shared__ float redw[4], redw2[4];
    __shared__ float redbuf[4][64];
    __shared__ float tmp64[64];
    int t = threadIdx.x, wave = t >> 6, lane = t & 63;
    int b = blockIdx.x;
    int s0 = bstart[b], e0 = bend[b];
    int cnt = e0 - s0;
    if (cnt < 0) cnt = 0;
    if (cnt > 1024) cnt = 1024;
    int ccnt = cnt < 192 ? cnt : 192;
    // ---- burst 1: node tile (<=192 rows -> <=3072 float4, 12 guarded/thread) ----
    int nf4 = ccnt * 16;
    const float4* out4 = (const float4*)(out + (size_t)s0 * 64);
    float4 stg[12];
    #pragma unroll
    for (int i = 0; i < 12; ++i) {
        int v = t + i * 256;
        if (v < nf4) stg[i] = out4[v];
    }
    #pragma unroll
    for (int i = 0; i < 12; ++i) {
        int v = t + i * 256;
        if (v < nf4) {
            int row = v >> 4, dq = v & 15;
            cacheT[(dq * 4 + 0) * 193 + row] = stg[i].x;
            cacheT[(dq * 4 + 1) * 193 + row] = stg[i].y;
            cacheT[(dq * 4 + 2) * 193 + row] = stg[i].z;
            cacheT[(dq * 4 + 3) * 193 + row] = stg[i].w;
        }
    }
    // ---- burst 2: post-MLP weights -> LDS (4112 float4 total) ----
    {
        float4* wp4 = (float4*)wpost;
        #pragma unroll
        for (int i = 0; i < 8; ++i) {            // pW0: 2048 float4
            int v = t + i * 256;
            wp4[v] = ((const float4*)pW0)[v];
        }
        #pragma unroll
        for (int i = 0; i < 4; ++i) {            // pW1: 1024 float4
            int v = t + i * 256;
            wp4[2048 + v] = ((const float4*)pW1)[v];
        }
        #pragma unroll
        for (int i = 0; i < 4; ++i) {            // pW2: 1024 float4
            int v = t + i * 256;
            wp4[3072 + v] = ((const float4*)pW2)[v];
        }
        if (t < 16) wp4[4096 + t] = ((const float4*)pW3)[t];
    }
    const float4* wihT4 = (const float4*)(WihT + (size_t)t * 128);
    const float4* whhT4 = (const float4*)(WhhT + (size_t)t * 64);
    float bsum = bih[t] + bhh[t];
    float ccr = 0.f;                       // cc for dim t (threads t<64 only)
    if (t < 128) qs[t] = 0.f;
    if (t < 64) hh_l[t] = 0.f;
    __syncthreads();
    const float4* qs4 = (const float4*)qs;
    const float4* hh4 = (const float4*)hh_l;
    for (int step = 0; step < 3; ++step) {
        // gates[t] = bias + qs . Wih[:,t] + hh . Whh[:,t]  (48 float4 burst, L2-hot)
        float g0 = bsum, g1 = 0.f, g2 = 0.f, g3 = 0.f;
        #pragma unroll
        for (int jq = 0; jq < 32; ++jq) {
            float4 w = wihT4[jq];
            float4 v = qs4[jq];
            g0 = fmaf(v.x, w.x, g0);
            g1 = fmaf(v.y, w.y, g1);
            g2 = fmaf(v.z, w.z, g2);
            g3 = fmaf(v.w, w.w, g3);
        }
        #pragma unroll
        for (int jq = 0; jq < 16; ++jq) {
            float4 w = whhT4[jq];
            float4 v = hh4[jq];
            g0 = fmaf(v.x, w.x, g0);
            g1 = fmaf(v.y, w.y, g1);
            g2 = fmaf(v.z, w.z, g2);
            g3 = fmaf(v.w, w.w, g3);
        }
        gates_l[t] = (g0 + g1) + (g2 + g3);
        __syncthreads();                                     // B1: gates ready
        if (t < 64) {
            float cn = sigf(gates_l[64 + t]) * ccr
                     + sigf(gates_l[t]) * tanhf(gates_l[128 + t]);
            ccr = cn;
            hh_l[t] = sigf(gates_l[192 + t]) * tanhf(cn);
        }
        __syncthreads();                                     // B2: hh ready
        // e[idx] = out_row . hh
        for (int idx = t; idx < cnt; idx += 256) {
            float s0a = 0.f, s1a = 0.f, s2a = 0.f, s3a = 0.f;
            if (idx < 192) {
                #pragma unroll
                for (int dq = 0; dq < 16; ++dq) {
                    float4 h = hh4[dq];
                    s0a = fmaf(cacheT[(dq * 4 + 0) * 193 + idx], h.x, s0a);
                    s1a = fmaf(cacheT[(dq * 4 + 1) * 193 + idx], h.y, s1a);
                    s2a = fmaf(cacheT[(dq * 4 + 2) * 193 + idx], h.z, s2a);
                    s3a = fmaf(cacheT[(dq * 4 + 3) * 193 + idx], h.w, s3a);
                }
            } else {
                const float* row = out + (size_t)(s0 + idx) * 64;
                #pragma unroll
                for (int dq = 0; dq < 16; ++dq) {
                    float4 h = hh4[dq];
                    s0a = fmaf(row[dq * 4 + 0], h.x, s0a);
                    s1a = fmaf(row[dq * 4 + 1], h.y, s1a);
                    s2a = fmaf(row[dq * 4 + 2], h.z, s2a);
                    s3a = fmaf(row[dq * 4 + 3], h.w, s3a);
                }
            }
            ebuf[idx] = (s0a + s1a) + (s2a + s3a);
        }
        __syncthreads();                                     // B3: e ready
        float lm = -3.0e38f;
        for (int idx = t; idx < cnt; idx += 256) lm = fmaxf(lm, ebuf[idx]);
        #pragma unroll
        for (int off = 32; off > 0; off >>= 1) lm = fmaxf(lm, __shfl_xor(lm, off, 64));
        if (lane == 0) redw[wave] = lm;
        __syncthreads();                                     // B4: wave maxes
        float m = fmaxf(fmaxf(redw[0], redw[1]), fmaxf(redw[2], redw[3]));
        float ls = 0.f;
        for (int idx = t; idx < cnt; idx += 256) {
            float a = __expf(ebuf[idx] - m);
            ebuf[idx] = a;
            ls += a;
        }
        #pragma unroll
        for (int off = 32; off > 0; off >>= 1) ls += __shfl_xor(ls, off, 64);
        if (lane == 0) redw2[wave] = ls;
        __syncthreads();                                     // B5: a's + wave sums
        float ssum = (redw2[0] + redw2[1]) + (redw2[2] + redw2[3]);
        float inv = (cnt > 0) ? 1.f / ssum : 0.f;
        // r[d=lane] = sum_row a[row]*node[row][d]; wave w handles rows w::4
        float r0 = 0.f;
        for (int row = wave; row < ccnt; row += 4)
            r0 = fmaf(ebuf[row], cacheT[lane * 193 + row], r0);
        for (int row = 192 + wave; row < cnt; row += 4)
            r0 = fmaf(ebuf[row], out[(size_t)(s0 + row) * 64 + lane], r0);
        redbuf[wave][lane] = r0;
        __syncthreads();                                     // B6: wave partials
        if (t < 64) {
            float s = ((redbuf[0][t] + redbuf[1][t]) + (redbuf[2][t] + redbuf[3][t]));
            qs[64 + t] = s * inv;
            qs[t] = hh_l[t];
        }
        __syncthreads();                                     // B7: qs ready
    }
    // post-MLP entirely from LDS weights (same k-ascending FMA order as before)
    if (t < 64) {
        float s = pb0[t];
        #pragma unroll 4
        for (int k = 0; k < 128; ++k) s = fmaf(qs[k], wpost[k * 64 + t], s);
        tmp64[t] = fmaxf(s, 0.f);
    }
    __syncthreads();
    float h1v = 0.f;
    if (t < 64) {
        float s = pb1[t];
        #pragma unroll 4
        for (int k = 0; k < 64; ++k) s = fmaf(tmp64[k], wpost[8192 + k * 64 + t], s);
        h1v = fmaxf(s, 0.f);
    }
    __syncthreads();
    if (t < 64) tmp64[t] = h1v;
    __syncthreads();
    if (t < 64) {
        float s = pb2[t];
        #pragma unroll 4
        for (int k = 0; k < 64; ++k) s = fmaf(tmp64[k], wpost[12288 + k * 64 + t], s);
        gates_l[t] = fmaxf(s, 0.f) * wpost[16384 + t];
    }
    __syncthreads();
    if (t == 0) {
        float yy = pb3[0];
        for (int k = 0; k < 64; ++k) yy += gates_l[k];
        y[b] = yy;
    }
}

// ---------------- host ----------------

extern "C" void kernel_launch(void* const* d_in, const int* in_sizes, int n_in,
                              void* d_out, int out_size, void* d_ws, size_t ws_size,
                              hipStream_t stream) {
    const float* x         = (const float*)d_in[0];
    const float* edge_attr = (const float*)d_in[1];
    const int*   edge_idx  = (const int*)d_in[2];
    const int*   batch_map = (const int*)d_in[3];
    const float* pre_W0 = (const float*)d_in[4];
    const float* pre_b0 = (const float*)d_in[5];
    const float* pre_W1 = (const float*)d_in[6];
    const float* pre_b1 = (const float*)d_in[7];
    const float* pre_W2 = (const float*)d_in[8];
    const float* pre_b2 = (const float*)d_in[9];
    const float* enn_W1 = (const float*)d_in[10];
    const float* enn_b1 = (const float*)d_in[11];
    const float* enn_W2 = (const float*)d_in[12];
    const float* enn_b2 = (const float*)d_in[13];
    const float* root_W = (const float*)d_in[14];
    const float* conv_b = (const float*)d_in[15];
    const float* gru_Wih = (const float*)d_in[16];
    const float* gru_Whh = (const float*)d_in[17];
    const float* gru_bih = (const float*)d_in[18];
    const float* gru_bhh = (const float*)d_in[19];
    const float* s2s_Wih = (const float*)d_in[20];
    const float* s2s_Whh = (const float*)d_in[21];
    const float* s2s_bih = (const float*)d_in[22];
    const float* s2s_bhh = (const float*)d_in[23];
    const float* post_W0 = (const float*)d_in[24];
    const float* post_b0 = (const float*)d_in[25];
    const float* post_W1 = (const float*)d_in[26];
    const float* post_b1 = (const float*)d_in[27];
    const float* post_W2 = (const float*)d_in[28];
    const float* post_b2 = (const float*)d_in[29];
    const float* post_W3 = (const float*)d_in[30];
    const float* post_b3 = (const float*)d_in[31];
    float* yout = (float*)d_out;

    char* wp = (char*)d_ws;
    auto take = [&](size_t bytes) -> char* {
        char* r = wp;
        wp += (bytes + 255) & ~(size_t)255;
        return r;
    };
    float* outA = (float*)take((size_t)NN * 64 * 4);
    float* outB = (float*)take((size_t)NN * 64 * 4);
    float* agg  = (float*)take((size_t)NN * 64 * 4);
    __hip_bfloat16* W2F = (__hip_bfloat16*)take((size_t)3 * 64 * 4096 * 2);
    int* cnt_src  = (int*)take((size_t)NN * 4);
    int* cnt_dst  = (int*)take((size_t)NN * 4);
    int* csr_dst  = (int*)take((size_t)NN * BKT * 4);
    float* csr_ea = (float*)take((size_t)NN * BKT * 4);
    int* bstart   = (int*)take((size_t)NB * 4);
    int* bend     = (int*)take((size_t)NB * 4);
    float* WihT   = (float*)take((size_t)256 * 128 * 4);
    float* WhhT   = (float*)take((size_t)256 * 64 * 4);

    k_setup<<<1248, 256, 0, stream>>>(x, pre_W0, pre_b0, pre_W1, pre_b1, pre_W2, pre_b2,
                                      enn_W2, W2F, outA, agg, cnt_src, cnt_dst,
                                      bstart, bend);
    k_bucket<<<160, 256, 0, stream>>>(edge_idx, edge_attr, batch_map,
                                      s2s_Wih, s2s_Whh, WihT, WhhT,
                                      cnt_src, cnt_dst, csr_dst, csr_ea, bstart, bend);

    float* cur = outA;
    float* nxt = outB;
    for (int l = 0; l < 3; ++l) {
        k_fused<<<NN / 8, 256, 0, stream>>>(cur, W2F + (size_t)l * 64 * 4096,
                                            enn_b2 + (size_t)l * 4096,
                                            enn_W1 + l * 64, enn_b1 + l * 64,
                                            cnt_src, csr_dst, csr_ea, agg);
        k_gru<<<NN / 4, 256, 0, stream>>>(cur, agg, cnt_dst, root_W + l * 4096,
                                          conv_b + l * 64, gru_Wih + l * 64 * 192,
                                          gru_Whh + l * 64 * 192, gru_bih + l * 192,
                                          gru_bhh + l * 192, nxt);
        float* tmp = cur; cur = nxt; nxt = tmp;
    }
    k_s2s_post<<<NB, 256, 0, stream>>>(cur, bstart, bend, WihT, WhhT, s2s_bih,
                                       s2s_bhh, post_W0, post_b0, post_W1, post_b1,
                                       post_W2, post_b2, post_W3, post_b3, yout);
}